// Round 3
// baseline (54.550 us; speedup 1.0000x reference)
//
#include <hip/hip_runtime.h>
#include <math.h>

constexpr int Bn = 32, Pn = 16, Ln = 512, Dn = 256, VOC = 50000;
constexpr int CHUNK = 128, NCH = 4;   // Ln / CHUNK

// --- Kernel A: eV[v] = emb[v,:]·V / 10 ; eW[v] = emb[v,:]·W / 10 ---
__global__ __launch_bounds__(256) void k_embdot(const float* __restrict__ emb,
                                               const float* __restrict__ V,
                                               const float* __restrict__ W,
                                               float* __restrict__ eV,
                                               float* __restrict__ eW)
{
    int row  = blockIdx.x * 4 + (threadIdx.x >> 6);   // one wave64 per vocab row
    if (row >= VOC) return;
    int lane = threadIdx.x & 63;
    float4 r  = ((const float4*)(emb + (size_t)row * Dn))[lane];
    float4 v  = ((const float4*)V)[lane];
    float4 w  = ((const float4*)W)[lane];
    float dv = r.x*v.x + r.y*v.y + r.z*v.z + r.w*v.w;
    float dw = r.x*w.x + r.y*w.y + r.z*w.z + r.w*w.w;
#pragma unroll
    for (int o = 32; o; o >>= 1) { dv += __shfl_xor(dv, o); dw += __shfl_xor(dw, o); }
    if (lane == 0) { eV[row] = dv / 10.0f; eW[row] = dw / 10.0f; }
}

// --- Kernel B: per-(b,p) word softmax + page score (256 thr, 2 tokens/thread) ---
__global__ __launch_bounds__(256) void k_score(const int* __restrict__ seq_ids,
                                               const int* __restrict__ num_pages,
                                               const int* __restrict__ seq_lengths,
                                               const float* __restrict__ eV,
                                               const float* __restrict__ eW,
                                               float* __restrict__ attn_out,
                                               float* __restrict__ pscore_out)
{
    int bp = blockIdx.x;                 // 0..511
    int b  = bp >> 4, p = bp & 15;
    int tid = threadIdx.x, lane = tid & 63, wv = tid >> 6;

    __shared__ float sc[Ln];
    __shared__ int   ids[Ln];
    __shared__ float redm[4], reds[4], redp[4];

    const int* sid = seq_ids + (size_t)bp * Ln;
    int  slen = seq_lengths[bp];
    bool vp   = (p < num_pages[b]);

    for (int l = tid; l < Ln; l += 256) {
        int id = sid[l];
        ids[l] = id;
        sc[l]  = (vp && l >= slen) ? -999.0f : eV[id];
    }
    __syncthreads();

    float mx = fmaxf(sc[tid], sc[tid + 256]);
#pragma unroll
    for (int o = 32; o; o >>= 1) mx = fmaxf(mx, __shfl_xor(mx, o));
    if (lane == 0) redm[wv] = mx;
    __syncthreads();
    mx = fmaxf(fmaxf(redm[0], redm[1]), fmaxf(redm[2], redm[3]));

    float e0 = expf(sc[tid] - mx);            // masked: expf(~-999) == exactly 0.0f
    float e1 = expf(sc[tid + 256] - mx);
    float sum = e0 + e1;
    float ps  = e0 * eW[ids[tid]] + e1 * eW[ids[tid + 256]];
#pragma unroll
    for (int o = 32; o; o >>= 1) { sum += __shfl_xor(sum, o); ps += __shfl_xor(ps, o); }
    if (lane == 0) { reds[wv] = sum; redp[wv] = ps; }
    __syncthreads();
    sum = reds[0] + reds[1] + reds[2] + reds[3];
    ps  = redp[0] + redp[1] + redp[2] + redp[3];
    float inv = 1.0f / sum;

    attn_out[(size_t)bp * Ln + tid]       = e0 * inv;
    attn_out[(size_t)bp * Ln + tid + 256] = e1 * inv;
    if (tid == 0) pscore_out[bp] = vp ? ps * inv : -9999.0f;
}

// --- Kernel C: chunked webpage_vec gather. block = (page bp, chunk c of 128 rows) ---
__global__ __launch_bounds__(256) void k_gather(const int* __restrict__ seq_ids,
                                                const int* __restrict__ num_pages,
                                                const int* __restrict__ seq_lengths,
                                                const float* __restrict__ emb,
                                                const float* __restrict__ attn,
                                                float* __restrict__ part)
{
    int bid = blockIdx.x;
    int bp = bid >> 2, c = bid & 3;
    int b  = bp >> 4,  p = bp & 15;
    int tid = threadIdx.x, lane = tid & 63, wv = tid >> 6;   // wv 0..3

    int  slen = seq_lengths[bp];
    int  Lv   = (p < num_pages[b]) ? slen : Ln;   // nonzero-attn prefix
    int  r0   = c * CHUNK;
    if (r0 >= Lv) return;                         // k_final skips these partials
    int  n    = min(CHUNK, Lv - r0);              // rows in this chunk

    __shared__ int   ids[CHUNK];
    __shared__ float w[CHUNK];
    __shared__ float partl[4][Dn];

    if (tid < CHUNK && tid < n) {
        ids[tid] = seq_ids[(size_t)bp * Ln + r0 + tid];
        w[tid]   = attn[(size_t)bp * Ln + r0 + tid];
    }
    __syncthreads();

    float4 acc = make_float4(0.f, 0.f, 0.f, 0.f);
    int s0 = wv * 32, s1 = min(s0 + 32, n);
#pragma unroll 8
    for (int i = s0; i < s1; ++i) {
        float4 v = ((const float4*)(emb + (size_t)ids[i] * Dn))[lane];
        float  ww = w[i];
        acc.x += ww * v.x; acc.y += ww * v.y; acc.z += ww * v.z; acc.w += ww * v.w;
    }
    ((float4*)partl[wv])[lane] = acc;
    __syncthreads();

    float s = partl[0][tid] + partl[1][tid] + partl[2][tid] + partl[3][tid];
    part[((size_t)bp * NCH + c) * Dn + tid] = s;
}

// --- Kernel D: sum chunk partials -> webpage_vec output ---
__global__ __launch_bounds__(256) void k_webred(const int* __restrict__ num_pages,
                                                const int* __restrict__ seq_lengths,
                                                const float* __restrict__ part,
                                                float* __restrict__ web)
{
    int bp = blockIdx.x;
    int b  = bp >> 4, p = bp & 15;
    int tid = threadIdx.x;
    int Lv  = (p < num_pages[b]) ? seq_lengths[bp] : Ln;
    int nch = (Lv + CHUNK - 1) / CHUNK;
    float s = 0.f;
    for (int c = 0; c < nch; ++c) s += part[((size_t)bp * NCH + c) * Dn + tid];
    web[(size_t)bp * Dn + tid] = s;
}

// --- Kernel E: sparsemax over pages, final vec, decoder, sigmoid ---
__global__ __launch_bounds__(256) void k_final(const float* __restrict__ dec_w,
                                               const float* __restrict__ pscore,
                                               const float* __restrict__ web,
                                               float* __restrict__ probs,
                                               float* __restrict__ senti,
                                               float* __restrict__ pattn,
                                               float* __restrict__ fvec)
{
    int b = blockIdx.x, tid = threadIdx.x, lane = tid & 63, wv = tid >> 6;
    __shared__ float pa[Pn];
    __shared__ float red[4];

    if (tid == 0) {
        float z[Pn], zs[Pn], csum[Pn];
        for (int i = 0; i < Pn; ++i) { z[i] = pscore[b * Pn + i]; zs[i] = z[i]; }
        for (int i = 1; i < Pn; ++i) {               // insertion sort descending
            float key = zs[i]; int j = i - 1;
            while (j >= 0 && zs[j] < key) { zs[j + 1] = zs[j]; --j; }
            zs[j + 1] = key;
        }
        int kmax = 0; float cs = 0.f;
        for (int k = 0; k < Pn; ++k) {
            cs += zs[k];
            csum[k] = cs;
            if (1.0f + (float)(k + 1) * zs[k] > cs) kmax = k + 1;
        }
        float tau = (csum[kmax - 1] - 1.0f) / (float)kmax;
        for (int i = 0; i < Pn; ++i) pa[i] = fmaxf(z[i] - tau, 0.0f);
    }
    __syncthreads();

    float fv = 0.f;
#pragma unroll
    for (int p = 0; p < Pn; ++p) fv += pa[p] * web[((size_t)b * Pn + p) * Dn + tid];
    fvec[(size_t)b * Dn + tid] = fv;
    if (tid < Pn) pattn[b * Pn + tid] = pa[tid];

    float t = fv * dec_w[tid];
#pragma unroll
    for (int o = 32; o; o >>= 1) t += __shfl_xor(t, o);
    if (lane == 0) red[wv] = t;
    __syncthreads();
    if (tid == 0) {
        float s = red[0] + red[1] + red[2] + red[3];
        senti[b] = s;
        probs[b] = 1.0f / (1.0f + expf(-s));
    }
}

extern "C" void kernel_launch(void* const* d_in, const int* in_sizes, int n_in,
                              void* d_out, int out_size, void* d_ws, size_t ws_size,
                              hipStream_t stream) {
    const int*   seq_ids     = (const int*)d_in[0];
    const int*   num_pages   = (const int*)d_in[1];
    const int*   seq_lengths = (const int*)d_in[2];
    const float* emb         = (const float*)d_in[3];
    const float* V           = (const float*)d_in[4];
    const float* W           = (const float*)d_in[5];
    const float* dec_w       = (const float*)d_in[6];

    float* out    = (float*)d_out;
    float* probs  = out;                                   // [B,1]     32
    float* senti  = probs + Bn;                            // [B,1]     32
    float* attn   = senti + Bn;                            // [B,P,1,L] 262144
    float* pattn  = attn  + (size_t)Bn * Pn * Ln;          // [B,1,P]   512
    float* fvec   = pattn + Bn * Pn;                       // [B,D]     8192
    float* pscore = fvec  + (size_t)Bn * Dn;               // [B,P]     512
    float* web    = pscore + Bn * Pn;                      // [B,P,D]   131072

    float* eV   = (float*)d_ws;                 // 50000 f32
    float* eW   = eV + VOC;                     // 50000 f32
    float* part = eW + VOC;                     // 512*4*256 f32 = 2 MB

    k_embdot<<<(VOC + 3) / 4, 256, 0, stream>>>(emb, V, W, eV, eW);
    k_score <<<Bn * Pn, 256, 0, stream>>>(seq_ids, num_pages, seq_lengths,
                                          eV, eW, attn, pscore);
    k_gather<<<Bn * Pn * NCH, 256, 0, stream>>>(seq_ids, num_pages, seq_lengths,
                                                emb, attn, part);
    k_webred<<<Bn * Pn, 256, 0, stream>>>(num_pages, seq_lengths, part, web);
    k_final <<<Bn, 256, 0, stream>>>(dec_w, pscore, web, probs, senti, pattn, fvec);
}

// Round 4
// 49.578 us; speedup vs baseline: 1.1003x; 1.1003x over previous
//
#include <hip/hip_runtime.h>
#include <math.h>

constexpr int Bn = 32, Pn = 16, Ln = 512, Dn = 256, VOC = 50000;

// --- Kernel A: eV[v] = emb[v,:]·V / 10 ; eW[v] = emb[v,:]·W / 10 ---
__global__ __launch_bounds__(256) void k_embdot(const float* __restrict__ emb,
                                               const float* __restrict__ V,
                                               const float* __restrict__ W,
                                               float* __restrict__ eV,
                                               float* __restrict__ eW)
{
    int row  = blockIdx.x * 4 + (threadIdx.x >> 6);   // one wave64 per vocab row
    if (row >= VOC) return;
    int lane = threadIdx.x & 63;
    float4 r  = ((const float4*)(emb + (size_t)row * Dn))[lane];
    float4 v  = ((const float4*)V)[lane];
    float4 w  = ((const float4*)W)[lane];
    float dv = r.x*v.x + r.y*v.y + r.z*v.z + r.w*v.w;
    float dw = r.x*w.x + r.y*w.y + r.z*w.z + r.w*w.w;
#pragma unroll
    for (int o = 32; o; o >>= 1) { dv += __shfl_xor(dv, o); dw += __shfl_xor(dw, o); }
    if (lane == 0) { eV[row] = dv / 10.0f; eW[row] = dw / 10.0f; }
}

// --- Kernel B: per-(b,p) softmax attention, page score, webpage_vec ---
// 1024 threads = 16 waves. Scoring uses lanes 0..511; gather interleaves the
// nonzero-prefix rows across all 16 waves (row l -> wave l%16), float4/lane.
__global__ __launch_bounds__(1024) void k_page(const int* __restrict__ seq_ids,
                                               const int* __restrict__ num_pages,
                                               const int* __restrict__ seq_lengths,
                                               const float* __restrict__ emb,
                                               const float* __restrict__ eV,
                                               const float* __restrict__ eW,
                                               float* __restrict__ attn_out,
                                               float* __restrict__ pscore_out,
                                               float* __restrict__ web_out)
{
    int bp = blockIdx.x;                 // 0..511
    int b  = bp >> 4, p = bp & 15;
    int tid = threadIdx.x, lane = tid & 63, wv = tid >> 6;   // wv 0..15

    __shared__ int   ids[Ln];
    __shared__ float sc[Ln];             // scores, then unnormalized exp(e)
    __shared__ float redm[16], reds[16], redp[16];
    __shared__ float part[16][Dn];       // 16 KB partial webpage_vec

    const int* sid = seq_ids + (size_t)bp * Ln;
    int  slen = seq_lengths[bp];
    bool vp   = (p < num_pages[b]);
    int  Lv   = vp ? slen : Ln;          // nonzero-attn prefix length

    // scores via eV gather (4B/token instead of 1KB/token)
    if (tid < Ln) {
        int id = sid[tid];
        ids[tid] = id;
        sc[tid]  = (vp && tid >= slen) ? -999.0f : eV[id];
    }
    __syncthreads();

    // block max over 512 scores
    float mx = (tid < Ln) ? sc[tid] : -1e30f;
#pragma unroll
    for (int o = 32; o; o >>= 1) mx = fmaxf(mx, __shfl_xor(mx, o));
    if (lane == 0) redm[wv] = mx;
    __syncthreads();
    mx = redm[0];
#pragma unroll
    for (int w = 1; w < 16; ++w) mx = fmaxf(mx, redm[w]);

    // exp (stored unnormalized), softmax denom, page-score numerator via eW
    float e = 0.f, pw = 0.f;
    if (tid < Ln) {
        e = expf(sc[tid] - mx);          // masked: expf(~-999) == exactly 0.0f
        sc[tid] = e;
        pw = e * eW[ids[tid]];
    }
    float sum = e, ps = pw;
#pragma unroll
    for (int o = 32; o; o >>= 1) { sum += __shfl_xor(sum, o); ps += __shfl_xor(ps, o); }
    if (lane == 0) { reds[wv] = sum; redp[wv] = ps; }
    __syncthreads();
    sum = 0.f; ps = 0.f;
#pragma unroll
    for (int w = 0; w < 16; ++w) { sum += reds[w]; ps += redp[w]; }
    float inv = 1.0f / sum;

    // attn output (normalized on the fly; no barrier needed — sc unchanged)
    if (tid < Ln) attn_out[(size_t)bp * Ln + tid] = sc[tid] * inv;
    if (tid == 0) pscore_out[bp] = vp ? ps * inv : -9999.0f;

    // webpage_vec: interleaved rows (l = wv, wv+16, ...) -> every wave does
    // ceil(Lv/16) rows regardless of Lv. Accumulate unnormalized, scale by inv.
    float4 acc = make_float4(0.f, 0.f, 0.f, 0.f);
#pragma unroll 4
    for (int l = wv; l < Lv; l += 16) {
        float4 v = ((const float4*)(emb + (size_t)ids[l] * Dn))[lane];
        float  w = sc[l];
        acc.x += w * v.x; acc.y += w * v.y; acc.z += w * v.z; acc.w += w * v.w;
    }
    acc.x *= inv; acc.y *= inv; acc.z *= inv; acc.w *= inv;
    ((float4*)part[wv])[lane] = acc;
    __syncthreads();

    if (tid < Dn) {
        float s = 0.f;
#pragma unroll
        for (int w = 0; w < 16; ++w) s += part[w][tid];
        web_out[(size_t)bp * Dn + tid] = s;
    }
}

// --- Kernel C: sparsemax over pages, final vec, decoder, sigmoid ---
__global__ __launch_bounds__(256) void k_final(const float* __restrict__ dec_w,
                                               const float* __restrict__ pscore,
                                               const float* __restrict__ web,
                                               float* __restrict__ probs,
                                               float* __restrict__ senti,
                                               float* __restrict__ pattn,
                                               float* __restrict__ fvec)
{
    int b = blockIdx.x, tid = threadIdx.x, lane = tid & 63, wv = tid >> 6;
    __shared__ float pa[Pn];
    __shared__ float red[4];

    if (tid == 0) {
        float z[Pn], zs[Pn], csum[Pn];
        for (int i = 0; i < Pn; ++i) { z[i] = pscore[b * Pn + i]; zs[i] = z[i]; }
        for (int i = 1; i < Pn; ++i) {               // insertion sort descending
            float key = zs[i]; int j = i - 1;
            while (j >= 0 && zs[j] < key) { zs[j + 1] = zs[j]; --j; }
            zs[j + 1] = key;
        }
        int kmax = 0; float cs = 0.f;
        for (int k = 0; k < Pn; ++k) {
            cs += zs[k];
            csum[k] = cs;
            if (1.0f + (float)(k + 1) * zs[k] > cs) kmax = k + 1;
        }
        float tau = (csum[kmax - 1] - 1.0f) / (float)kmax;
        for (int i = 0; i < Pn; ++i) pa[i] = fmaxf(z[i] - tau, 0.0f);
    }
    __syncthreads();

    float fv = 0.f;
#pragma unroll
    for (int p = 0; p < Pn; ++p) fv += pa[p] * web[((size_t)b * Pn + p) * Dn + tid];
    fvec[(size_t)b * Dn + tid] = fv;
    if (tid < Pn) pattn[b * Pn + tid] = pa[tid];

    float t = fv * dec_w[tid];
#pragma unroll
    for (int o = 32; o; o >>= 1) t += __shfl_xor(t, o);
    if (lane == 0) red[wv] = t;
    __syncthreads();
    if (tid == 0) {
        float s = red[0] + red[1] + red[2] + red[3];
        senti[b] = s;
        probs[b] = 1.0f / (1.0f + expf(-s));
    }
}

extern "C" void kernel_launch(void* const* d_in, const int* in_sizes, int n_in,
                              void* d_out, int out_size, void* d_ws, size_t ws_size,
                              hipStream_t stream) {
    const int*   seq_ids     = (const int*)d_in[0];
    const int*   num_pages   = (const int*)d_in[1];
    const int*   seq_lengths = (const int*)d_in[2];
    const float* emb         = (const float*)d_in[3];
    const float* V           = (const float*)d_in[4];
    const float* W           = (const float*)d_in[5];
    const float* dec_w       = (const float*)d_in[6];

    float* out    = (float*)d_out;
    float* probs  = out;                                   // [B,1]     32
    float* senti  = probs + Bn;                            // [B,1]     32
    float* attn   = senti + Bn;                            // [B,P,1,L] 262144
    float* pattn  = attn  + (size_t)Bn * Pn * Ln;          // [B,1,P]   512
    float* fvec   = pattn + Bn * Pn;                       // [B,D]     8192
    float* pscore = fvec  + (size_t)Bn * Dn;               // [B,P]     512
    float* web    = pscore + Bn * Pn;                      // [B,P,D]   131072

    float* eV = (float*)d_ws;          // 50000 f32
    float* eW = eV + VOC;              // 50000 f32  (400 KB total)

    k_embdot<<<(VOC + 3) / 4, 256, 0, stream>>>(emb, V, W, eV, eW);
    k_page<<<Bn * Pn, 1024, 0, stream>>>(seq_ids, num_pages, seq_lengths,
                                         emb, eV, eW, attn, pscore, web);
    k_final<<<Bn, 256, 0, stream>>>(dec_w, pscore, web, probs, senti, pattn, fvec);
}

// Round 5
// 40.165 us; speedup vs baseline: 1.3581x; 1.2343x over previous
//
#include <hip/hip_runtime.h>
#include <math.h>

constexpr int Bn = 32, Pn = 16, Ln = 512, Dn = 256, VOC = 50000;

// --- Kernel A: eVW[v] = {emb[v]·V, emb[v]·W}/10 ; bt[v] = bf16(emb[v]) ---
__global__ __launch_bounds__(256) void k_embdot(const float* __restrict__ emb,
                                               const float* __restrict__ V,
                                               const float* __restrict__ W,
                                               float2* __restrict__ eVW,
                                               ushort* __restrict__ bt)
{
    int row  = blockIdx.x * 4 + (threadIdx.x >> 6);   // one wave64 per vocab row
    if (row >= VOC) return;
    int lane = threadIdx.x & 63;
    float4 r  = ((const float4*)(emb + (size_t)row * Dn))[lane];
    float4 v  = ((const float4*)V)[lane];
    float4 w  = ((const float4*)W)[lane];

    // bf16 (RNE) shadow copy: 4 elems/lane = 8B/lane, coalesced 512B/wave
    uint u0 = __float_as_uint(r.x), u1 = __float_as_uint(r.y),
         u2 = __float_as_uint(r.z), u3 = __float_as_uint(r.w);
    ushort4 h;
    h.x = (ushort)((u0 + 0x7fffu + ((u0 >> 16) & 1u)) >> 16);
    h.y = (ushort)((u1 + 0x7fffu + ((u1 >> 16) & 1u)) >> 16);
    h.z = (ushort)((u2 + 0x7fffu + ((u2 >> 16) & 1u)) >> 16);
    h.w = (ushort)((u3 + 0x7fffu + ((u3 >> 16) & 1u)) >> 16);
    *(ushort4*)(bt + (size_t)row * Dn + lane * 4) = h;

    float dv = r.x*v.x + r.y*v.y + r.z*v.z + r.w*v.w;
    float dw = r.x*w.x + r.y*w.y + r.z*w.z + r.w*w.w;
#pragma unroll
    for (int o = 32; o; o >>= 1) { dv += __shfl_xor(dv, o); dw += __shfl_xor(dw, o); }
    if (lane == 0) eVW[row] = make_float2(dv / 10.0f, dw / 10.0f);
}

// --- Kernel B: per-(b,p) softmax attention, page score, webpage_vec ---
// 1024 threads = 16 waves. Score phase: lanes 0..511, one 8B eVW gather each
// (eW kept in-register). Gather phase: 32 row-streams (half-wave = one bf16
// row, 16B/lane), rows interleaved l = s, s+32, ...
__global__ __launch_bounds__(1024) void k_page(const int* __restrict__ seq_ids,
                                               const int* __restrict__ num_pages,
                                               const int* __restrict__ seq_lengths,
                                               const ushort* __restrict__ bt,
                                               const float2* __restrict__ eVW,
                                               float* __restrict__ attn_out,
                                               float* __restrict__ pscore_out,
                                               float* __restrict__ web_out)
{
    int bp = blockIdx.x;                 // 0..511
    int b  = bp >> 4, p = bp & 15;
    int tid = threadIdx.x, lane = tid & 63, wv = tid >> 6;   // wv 0..15

    __shared__ int   ids[Ln];
    __shared__ float sc[Ln];             // scores, then unnormalized exp(e)
    __shared__ float redm[16], reds[16], redp[16];
    __shared__ float part[32][Dn];       // 32 KB per-stream partial webpage_vec

    const int* sid = seq_ids + (size_t)bp * Ln;
    int  slen = seq_lengths[bp];
    bool vp   = (p < num_pages[b]);
    int  Lv   = vp ? slen : Ln;          // nonzero-attn prefix length

    // scores via single 8B eVW gather; keep eW in register for phase 2
    float wreg = 0.f;
    if (tid < Ln) {
        int id = sid[tid];
        ids[tid] = id;
        float2 vw = eVW[id];
        wreg = vw.y;
        sc[tid] = (vp && tid >= slen) ? -999.0f : vw.x;
    }
    __syncthreads();

    // block max over 512 scores
    float mx = (tid < Ln) ? sc[tid] : -1e30f;
#pragma unroll
    for (int o = 32; o; o >>= 1) mx = fmaxf(mx, __shfl_xor(mx, o));
    if (lane == 0) redm[wv] = mx;
    __syncthreads();
    mx = redm[0];
#pragma unroll
    for (int w = 1; w < 16; ++w) mx = fmaxf(mx, redm[w]);

    // exp (stored unnormalized), softmax denom, page-score numerator (register eW)
    float e = 0.f, pw = 0.f;
    if (tid < Ln) {
        e = expf(sc[tid] - mx);          // masked: expf(~-999) == exactly 0.0f
        sc[tid] = e;
        pw = e * wreg;
    }
    float sum = e, ps = pw;
#pragma unroll
    for (int o = 32; o; o >>= 1) { sum += __shfl_xor(sum, o); ps += __shfl_xor(ps, o); }
    if (lane == 0) { reds[wv] = sum; redp[wv] = ps; }
    __syncthreads();
    sum = 0.f; ps = 0.f;
#pragma unroll
    for (int w = 0; w < 16; ++w) { sum += reds[w]; ps += redp[w]; }
    float inv = 1.0f / sum;

    // attn output (sc[] unchanged afterwards -> no extra barrier needed)
    if (tid < Ln) attn_out[(size_t)bp * Ln + tid] = sc[tid] * inv;
    if (tid == 0) pscore_out[bp] = vp ? ps * inv : -9999.0f;

    // webpage_vec gather from bf16 rows: stream s = 2*wv + (lane>>5) handles
    // rows s, s+32, ... ; 32 lanes per row, 16B (8 bf16 cols) per lane.
    int s  = 2 * wv + (lane >> 5);
    int cl = lane & 31;
    float a0=0.f,a1=0.f,a2=0.f,a3=0.f,a4=0.f,a5=0.f,a6=0.f,a7=0.f;
#pragma unroll 4
    for (int l = s; l < Lv; l += 32) {
        float wgt = sc[l];
        uint4 q = *(const uint4*)(bt + (size_t)ids[l] * Dn + cl * 8);
        a0 += wgt * __uint_as_float(q.x << 16);
        a1 += wgt * __uint_as_float(q.x & 0xffff0000u);
        a2 += wgt * __uint_as_float(q.y << 16);
        a3 += wgt * __uint_as_float(q.y & 0xffff0000u);
        a4 += wgt * __uint_as_float(q.z << 16);
        a5 += wgt * __uint_as_float(q.z & 0xffff0000u);
        a6 += wgt * __uint_as_float(q.w << 16);
        a7 += wgt * __uint_as_float(q.w & 0xffff0000u);
    }
    float4 lo = make_float4(a0*inv, a1*inv, a2*inv, a3*inv);
    float4 hi = make_float4(a4*inv, a5*inv, a6*inv, a7*inv);
    ((float4*)&part[s][cl * 8])[0] = lo;
    ((float4*)&part[s][cl * 8])[1] = hi;
    __syncthreads();

    if (tid < Dn) {
        float acc = 0.f;
#pragma unroll
        for (int w = 0; w < 32; ++w) acc += part[w][tid];
        web_out[(size_t)bp * Dn + tid] = acc;
    }
}

// --- Kernel C: sparsemax over pages, final vec, decoder, sigmoid ---
__global__ __launch_bounds__(256) void k_final(const float* __restrict__ dec_w,
                                               const float* __restrict__ pscore,
                                               const float* __restrict__ web,
                                               float* __restrict__ probs,
                                               float* __restrict__ senti,
                                               float* __restrict__ pattn,
                                               float* __restrict__ fvec)
{
    int b = blockIdx.x, tid = threadIdx.x, lane = tid & 63, wv = tid >> 6;
    __shared__ float pa[Pn];
    __shared__ float red[4];

    if (tid == 0) {
        float z[Pn], zs[Pn], csum[Pn];
        for (int i = 0; i < Pn; ++i) { z[i] = pscore[b * Pn + i]; zs[i] = z[i]; }
        for (int i = 1; i < Pn; ++i) {               // insertion sort descending
            float key = zs[i]; int j = i - 1;
            while (j >= 0 && zs[j] < key) { zs[j + 1] = zs[j]; --j; }
            zs[j + 1] = key;
        }
        int kmax = 0; float cs = 0.f;
        for (int k = 0; k < Pn; ++k) {
            cs += zs[k];
            csum[k] = cs;
            if (1.0f + (float)(k + 1) * zs[k] > cs) kmax = k + 1;
        }
        float tau = (csum[kmax - 1] - 1.0f) / (float)kmax;
        for (int i = 0; i < Pn; ++i) pa[i] = fmaxf(z[i] - tau, 0.0f);
    }
    __syncthreads();

    float fv = 0.f;
#pragma unroll
    for (int p = 0; p < Pn; ++p) fv += pa[p] * web[((size_t)b * Pn + p) * Dn + tid];
    fvec[(size_t)b * Dn + tid] = fv;
    if (tid < Pn) pattn[b * Pn + tid] = pa[tid];

    float t = fv * dec_w[tid];
#pragma unroll
    for (int o = 32; o; o >>= 1) t += __shfl_xor(t, o);
    if (lane == 0) red[wv] = t;
    __syncthreads();
    if (tid == 0) {
        float s = red[0] + red[1] + red[2] + red[3];
        senti[b] = s;
        probs[b] = 1.0f / (1.0f + expf(-s));
    }
}

extern "C" void kernel_launch(void* const* d_in, const int* in_sizes, int n_in,
                              void* d_out, int out_size, void* d_ws, size_t ws_size,
                              hipStream_t stream) {
    const int*   seq_ids     = (const int*)d_in[0];
    const int*   num_pages   = (const int*)d_in[1];
    const int*   seq_lengths = (const int*)d_in[2];
    const float* emb         = (const float*)d_in[3];
    const float* V           = (const float*)d_in[4];
    const float* W           = (const float*)d_in[5];
    const float* dec_w       = (const float*)d_in[6];

    float* out    = (float*)d_out;
    float* probs  = out;                                   // [B,1]     32
    float* senti  = probs + Bn;                            // [B,1]     32
    float* attn   = senti + Bn;                            // [B,P,1,L] 262144
    float* pattn  = attn  + (size_t)Bn * Pn * Ln;          // [B,1,P]   512
    float* fvec   = pattn + Bn * Pn;                       // [B,D]     8192
    float* pscore = fvec  + (size_t)Bn * Dn;               // [B,P]     512
    float* web    = pscore + Bn * Pn;                      // [B,P,D]   131072

    float2* eVW = (float2*)d_ws;                           // VOC float2 = 400 KB
    ushort* bt  = (ushort*)((char*)d_ws + (size_t)VOC * sizeof(float2)); // 25.6 MB bf16 table

    k_embdot<<<(VOC + 3) / 4, 256, 0, stream>>>(emb, V, W, eVW, bt);
    k_page<<<Bn * Pn, 1024, 0, stream>>>(seq_ids, num_pages, seq_lengths,
                                         bt, eVW, attn, pscore, web);
    k_final<<<Bn, 256, 0, stream>>>(dec_w, pscore, web, probs, senti, pattn, fvec);
}

// Round 6
// 39.235 us; speedup vs baseline: 1.3903x; 1.0237x over previous
//
#include <hip/hip_runtime.h>
#include <math.h>

constexpr int Bn = 32, Pn = 16, Ln = 512, Dn = 256, VOC = 50000;

// --- Kernel A: eVW[v] = {emb[v]·V, emb[v]·W}/10 ; bt[v] = bf16(emb[v]) ---
__global__ __launch_bounds__(256) void k_embdot(const float* __restrict__ emb,
                                               const float* __restrict__ V,
                                               const float* __restrict__ W,
                                               float2* __restrict__ eVW,
                                               ushort* __restrict__ bt)
{
    int row  = blockIdx.x * 4 + (threadIdx.x >> 6);   // one wave64 per vocab row
    if (row >= VOC) return;
    int lane = threadIdx.x & 63;
    float4 r  = ((const float4*)(emb + (size_t)row * Dn))[lane];
    float4 v  = ((const float4*)V)[lane];
    float4 w  = ((const float4*)W)[lane];

    // bf16 (RNE) shadow copy: 4 elems/lane = 8B/lane, coalesced 512B/wave
    uint u0 = __float_as_uint(r.x), u1 = __float_as_uint(r.y),
         u2 = __float_as_uint(r.z), u3 = __float_as_uint(r.w);
    ushort4 h;
    h.x = (ushort)((u0 + 0x7fffu + ((u0 >> 16) & 1u)) >> 16);
    h.y = (ushort)((u1 + 0x7fffu + ((u1 >> 16) & 1u)) >> 16);
    h.z = (ushort)((u2 + 0x7fffu + ((u2 >> 16) & 1u)) >> 16);
    h.w = (ushort)((u3 + 0x7fffu + ((u3 >> 16) & 1u)) >> 16);
    *(ushort4*)(bt + (size_t)row * Dn + lane * 4) = h;

    float dv = r.x*v.x + r.y*v.y + r.z*v.z + r.w*v.w;
    float dw = r.x*w.x + r.y*w.y + r.z*w.z + r.w*w.w;
#pragma unroll
    for (int o = 32; o; o >>= 1) { dv += __shfl_xor(dv, o); dw += __shfl_xor(dw, o); }
    if (lane == 0) eVW[row] = make_float2(dv / 10.0f, dw / 10.0f);
}

// --- Kernel B: per-(b,p) softmax attention, page score, webpage_vec ---
// 512 threads = 8 waves. Score: exactly one token/thread (no idle lanes).
// Gather: 16 row-streams (half-wave = one bf16 row, 16B/lane), stride 16.
__global__ __launch_bounds__(512) void k_page(const int* __restrict__ seq_ids,
                                              const int* __restrict__ num_pages,
                                              const int* __restrict__ seq_lengths,
                                              const ushort* __restrict__ bt,
                                              const float2* __restrict__ eVW,
                                              float* __restrict__ attn_out,
                                              float* __restrict__ pscore_out,
                                              float* __restrict__ web_out)
{
    int bp = blockIdx.x;                 // 0..511
    int b  = bp >> 4, p = bp & 15;
    int tid = threadIdx.x, lane = tid & 63, wv = tid >> 6;   // wv 0..7

    __shared__ int   ids[Ln];
    __shared__ float sc[Ln];             // scores, then unnormalized exp(e)
    __shared__ float redm[8], reds[8], redp[8];
    __shared__ float part[16][Dn];       // 16 KB per-stream partial webpage_vec

    const int* sid = seq_ids + (size_t)bp * Ln;
    int  slen = seq_lengths[bp];
    bool vp   = (p < num_pages[b]);
    int  Lv   = vp ? slen : Ln;          // nonzero-attn prefix length

    // scores via single 8B eVW gather; keep eW in register for phase 2
    int id = sid[tid];
    ids[tid] = id;
    float2 vw = eVW[id];
    float wreg = vw.y;
    sc[tid] = (vp && tid >= slen) ? -999.0f : vw.x;
    __syncthreads();

    // block max over 512 scores
    float mx = sc[tid];
#pragma unroll
    for (int o = 32; o; o >>= 1) mx = fmaxf(mx, __shfl_xor(mx, o));
    if (lane == 0) redm[wv] = mx;
    __syncthreads();
    mx = redm[0];
#pragma unroll
    for (int w = 1; w < 8; ++w) mx = fmaxf(mx, redm[w]);

    // exp (stored unnormalized), softmax denom, page-score numerator (register eW)
    float e = expf(sc[tid] - mx);        // masked: expf(~-999) == exactly 0.0f
    sc[tid] = e;
    float pw = e * wreg;
    float sum = e, ps = pw;
#pragma unroll
    for (int o = 32; o; o >>= 1) { sum += __shfl_xor(sum, o); ps += __shfl_xor(ps, o); }
    if (lane == 0) { reds[wv] = sum; redp[wv] = ps; }
    __syncthreads();
    sum = 0.f; ps = 0.f;
#pragma unroll
    for (int w = 0; w < 8; ++w) { sum += reds[w]; ps += redp[w]; }
    float inv = 1.0f / sum;

    // attn output (sc[] unchanged afterwards -> no extra barrier needed)
    attn_out[(size_t)bp * Ln + tid] = sc[tid] * inv;
    if (tid == 0) pscore_out[bp] = vp ? ps * inv : -9999.0f;

    // webpage_vec gather from bf16 rows: stream s = 2*wv + (lane>>5) handles
    // rows s, s+16, ... ; 32 lanes per row, 16B (8 bf16 cols) per lane.
    int s  = 2 * wv + (lane >> 5);
    int cl = lane & 31;
    float a0=0.f,a1=0.f,a2=0.f,a3=0.f,a4=0.f,a5=0.f,a6=0.f,a7=0.f;
#pragma unroll 4
    for (int l = s; l < Lv; l += 16) {
        float wgt = sc[l];
        uint4 q = *(const uint4*)(bt + (size_t)ids[l] * Dn + cl * 8);
        a0 += wgt * __uint_as_float(q.x << 16);
        a1 += wgt * __uint_as_float(q.x & 0xffff0000u);
        a2 += wgt * __uint_as_float(q.y << 16);
        a3 += wgt * __uint_as_float(q.y & 0xffff0000u);
        a4 += wgt * __uint_as_float(q.z << 16);
        a5 += wgt * __uint_as_float(q.z & 0xffff0000u);
        a6 += wgt * __uint_as_float(q.w << 16);
        a7 += wgt * __uint_as_float(q.w & 0xffff0000u);
    }
    float4 lo = make_float4(a0*inv, a1*inv, a2*inv, a3*inv);
    float4 hi = make_float4(a4*inv, a5*inv, a6*inv, a7*inv);
    ((float4*)&part[s][cl * 8])[0] = lo;
    ((float4*)&part[s][cl * 8])[1] = hi;
    __syncthreads();

    // cross-stream reduce: threads 0..255 each own one output column
    if (tid < Dn) {
        float acc = 0.f;
#pragma unroll
        for (int w = 0; w < 16; ++w) acc += part[w][tid];
        web_out[(size_t)bp * Dn + tid] = acc;
    }
}

// --- Kernel C: sparsemax over pages, final vec, decoder, sigmoid ---
__global__ __launch_bounds__(256) void k_final(const float* __restrict__ dec_w,
                                               const float* __restrict__ pscore,
                                               const float* __restrict__ web,
                                               float* __restrict__ probs,
                                               float* __restrict__ senti,
                                               float* __restrict__ pattn,
                                               float* __restrict__ fvec)
{
    int b = blockIdx.x, tid = threadIdx.x, lane = tid & 63, wv = tid >> 6;
    __shared__ float pa[Pn];
    __shared__ float red[4];

    if (tid == 0) {
        float z[Pn], zs[Pn], csum[Pn];
        for (int i = 0; i < Pn; ++i) { z[i] = pscore[b * Pn + i]; zs[i] = z[i]; }
        for (int i = 1; i < Pn; ++i) {               // insertion sort descending
            float key = zs[i]; int j = i - 1;
            while (j >= 0 && zs[j] < key) { zs[j + 1] = zs[j]; --j; }
            zs[j + 1] = key;
        }
        int kmax = 0; float cs = 0.f;
        for (int k = 0; k < Pn; ++k) {
            cs += zs[k];
            csum[k] = cs;
            if (1.0f + (float)(k + 1) * zs[k] > cs) kmax = k + 1;
        }
        float tau = (csum[kmax - 1] - 1.0f) / (float)kmax;
        for (int i = 0; i < Pn; ++i) pa[i] = fmaxf(z[i] - tau, 0.0f);
    }
    __syncthreads();

    float fv = 0.f;
#pragma unroll
    for (int p = 0; p < Pn; ++p) fv += pa[p] * web[((size_t)b * Pn + p) * Dn + tid];
    fvec[(size_t)b * Dn + tid] = fv;
    if (tid < Pn) pattn[b * Pn + tid] = pa[tid];

    float t = fv * dec_w[tid];
#pragma unroll
    for (int o = 32; o; o >>= 1) t += __shfl_xor(t, o);
    if (lane == 0) red[wv] = t;
    __syncthreads();
    if (tid == 0) {
        float s = red[0] + red[1] + red[2] + red[3];
        senti[b] = s;
        probs[b] = 1.0f / (1.0f + expf(-s));
    }
}

extern "C" void kernel_launch(void* const* d_in, const int* in_sizes, int n_in,
                              void* d_out, int out_size, void* d_ws, size_t ws_size,
                              hipStream_t stream) {
    const int*   seq_ids     = (const int*)d_in[0];
    const int*   num_pages   = (const int*)d_in[1];
    const int*   seq_lengths = (const int*)d_in[2];
    const float* emb         = (const float*)d_in[3];
    const float* V           = (const float*)d_in[4];
    const float* W           = (const float*)d_in[5];
    const float* dec_w       = (const float*)d_in[6];

    float* out    = (float*)d_out;
    float* probs  = out;                                   // [B,1]     32
    float* senti  = probs + Bn;                            // [B,1]     32
    float* attn   = senti + Bn;                            // [B,P,1,L] 262144
    float* pattn  = attn  + (size_t)Bn * Pn * Ln;          // [B,1,P]   512
    float* fvec   = pattn + Bn * Pn;                       // [B,D]     8192
    float* pscore = fvec  + (size_t)Bn * Dn;               // [B,P]     512
    float* web    = pscore + Bn * Pn;                      // [B,P,D]   131072

    float2* eVW = (float2*)d_ws;                           // VOC float2 = 400 KB
    ushort* bt  = (ushort*)((char*)d_ws + (size_t)VOC * sizeof(float2)); // 25.6 MB bf16 table

    k_embdot<<<(VOC + 3) / 4, 256, 0, stream>>>(emb, V, W, eVW, bt);
    k_page<<<Bn * Pn, 512, 0, stream>>>(seq_ids, num_pages, seq_lengths,
                                        bt, eVW, attn, pscore, web);
    k_final<<<Bn, 256, 0, stream>>>(dec_w, pscore, web, probs, senti, pattn, fvec);
}